// Round 3
// baseline (102.847 us; speedup 1.0000x reference)
//
#include <hip/hip_runtime.h>

// PrRoIPool2D forward, MI355X. B=8, C=256, H=W=48, R=300, 7x7 bins, scale=1/16.
// R13: persistent pipelined blocks (T14 issue-early/write-late across items).
//  - grid 768 (3 blocks/CU, zero tail), each block owns 12-13 consecutive
//    items (item = r*32 + cblk); same-r runs skip weight recompute.
//  - per item k: loads for k+1 issued right after bar1(k) into regs (pf),
//    ds-written to patch after PB(k) -> HBM latency hides under PA+bar+PB.
//    Cold-load latency exposed once per block (prologue), not once per item.
//  - hazards: patch write(k+1) after bar2(k) [PA(k) done]; rs write(k+1)
//    after bar1(k+1) [PB(k) done]; pbuf rewritten only on r-change behind an
//    extra uniform barrier. 2 barriers/item steady-state.
//  - XOR-swizzled patch/rs kept (LDS may become critical in pipelined regime).
// Numerics identical to R10-R12 (same arithmetic forms/order). LDS 25.5 KB.

#define PH 7
#define PW 7
#define NBINS 49
#define SCALE 0.0625f
#define CH 256
#define FH 48
#define FW 48
#define RNUM 300
#define CB 8                 // channels per block-item
#define MAXJ 23              // max patch rows
#define NL 7                 // 16B cells per row
#define NBLK 768             // 3 blocks/CU * 256 CU

__device__ __forceinline__ float hat_int(float x, float g) {
    float t = x - (g - 1.0f);
    if (t <= 0.0f) return 0.0f;
    if (t <= 1.0f) return 0.5f * t * t;
    if (t <= 2.0f) { float u = 2.0f - t; return 1.0f - 0.5f * u * u; }
    return 1.0f;
}

__global__ __launch_bounds__(256, 3)
void prroi_pers(const float* __restrict__ feat,
                const float* __restrict__ rois,
                float* __restrict__ out) {
    const int tid  = threadIdx.x;
    const int blk  = blockIdx.x;
    const int base = blk * 12 + min(blk, 384);   // 384 blocks get 13 items
    const int n    = (blk < 384) ? 13 : 12;      // 384*13 + 384*12 = 9600

    __shared__ float patch[MAXJ * NL * 32];      // swizzled, 20608 B
    __shared__ float rs[PW * MAXJ * CB];         // swizzled halves, 5152 B
    __shared__ float pbuf[99];                   // wy/bj/inv_area, 396 B

    // ---- NXT item state (bounds) ----
    int rN = 0, c0N = 0, J0N = 0, I0N = 0, JRN = 6, NI4N = 2;
    float x1N = 0, y1N = 0, x2N = 0, y2N = 0, bwN = 0, bhN = 0, iaN = 0;
    const float* fbN = feat;

    auto DECODE = [&](int it) {
        rN  = it >> 5;
        c0N = (it & 31) << 3;
        const float* roi = rois + rN * 5;
        const int b = (int)roi[0];
        x1N = roi[1] * SCALE; y1N = roi[2] * SCALE;
        x2N = roi[3] * SCALE; y2N = roi[4] * SCALE;
        const float ylo = fminf(y1N, y2N), yhi = fmaxf(y1N, y2N);
        const float xlo = fminf(x1N, x2N), xhi = fmaxf(x1N, x2N);
        const int j1 = min(FH - 1, (int)floorf(yhi) + 1);
        const int i1 = min(FW - 1, (int)floorf(xhi) + 1);
        J0N = min(max(0, (int)floorf(ylo) - 1), FH - 6);
        I0N = min(max(0, (int)floorf(xlo) - 1) & ~3, FW - 8);
        JRN = min(FH - J0N, max(j1 - J0N + 1, 6));               // 6..23
        int ni = min(((i1 - I0N) >> 2) + 1, (FW - I0N) >> 2);
        NI4N = max(ni, 2);                                        // 2..7
        bwN = fmaxf(x2N - x1N, 0.0f) / (float)PW;                 // keep /7.0f form
        bhN = fmaxf(y2N - y1N, 0.0f) / (float)PH;
        const float area = bwN * bhN;
        iaN = (area > 0.0f) ? (1.0f / area) : 0.0f;
        fbN = feat + (size_t)(b * CH + c0N) * FH * FW;
    };

    // ---- PA state (valid for item with r == cur weight r) ----
    bool a1 = false, a2 = false;
    int j1r = 0, pw1 = 0, q1 = 0, bi1 = 0, j2r = 0, pw2 = 0, q2 = 0, bi2 = 0;
    float wxa[6], wxb[6];
    auto CALC_WX = [&]() {
        const int nA = JRN * 14;
        a1 = tid < nA; a2 = (tid + 256) < nA;
        if (a1) {
            j1r = tid / 14; const int rem = tid - j1r * 14; pw1 = rem >> 1; q1 = rem & 1;
            const float xa = x1N + pw1 * bwN, xb = xa + bwN;
            const int bse = min(max((int)floorf(xa) - 1, I0N), I0N + 4 * NI4N - 6);
            bi1 = bse - I0N;
#pragma unroll
            for (int kk = 0; kk < 6; ++kk) {
                const float g = (float)(bse + kk);
                wxa[kk] = hat_int(xb, g) - hat_int(xa, g);
            }
        }
        if (a2) {
            const int v2 = tid + 256;
            j2r = v2 / 14; const int rem = v2 - j2r * 14; pw2 = rem >> 1; q2 = rem & 1;
            const float xa = x1N + pw2 * bwN, xb = xa + bwN;
            const int bse = min(max((int)floorf(xa) - 1, I0N), I0N + 4 * NI4N - 6);
            bi2 = bse - I0N;
#pragma unroll
            for (int kk = 0; kk < 6; ++kk) {
                const float g = (float)(bse + kk);
                wxb[kk] = hat_int(xb, g) - hat_int(xa, g);
            }
        }
    };

    auto CALC_WY = [&]() {
        if (tid < PH) {
            const float ya = y1N + tid * bhN, yb = ya + bhN;
            const int bse = min(max((int)floorf(ya) - 1, J0N), J0N + JRN - 6);
            pbuf[84 + tid] = __int_as_float(bse - J0N);
#pragma unroll
            for (int kk = 0; kk < 6; ++kk) {
                const float g = (float)(bse + kk);
                pbuf[tid * 6 + kk] = hat_int(yb, g) - hat_int(ya, g);
            }
        } else if (tid == PH) {
            pbuf[98] = iaN;
        }
    };

    // ---- prefetch regs + P1 unit state (for the item described by NXT) ----
    float4 pf[2][4];
    int u_dl[2], u_q[2], u_m[2];
    bool u_a[2];
    auto ISSUE = [&]() {
        const int J7 = JRN * NL;
#pragma unroll
        for (int s = 0; s < 2; ++s) {
            const int v = tid + (s << 8);
            bool act = v < 2 * J7;
            if (act) {
                const int q  = (v >= J7) ? 1 : 0;
                const int rm = v - (q ? J7 : 0);
                const int j  = rm / NL;
                const int i4 = rm - j * NL;
                act = i4 < NI4N;
                u_q[s]  = q;
                u_m[s]  = (j + i4) & 7;
                u_dl[s] = (j * NL + i4) * 32;
                if (act) {
                    const float* src = fbN +
                        ((size_t)((q << 2) * FH + (J0N + j)) * FW) + I0N + (i4 << 2);
                    pf[s][0] = *(const float4*)(src);
                    pf[s][1] = *(const float4*)(src + FH * FW);
                    pf[s][2] = *(const float4*)(src + 2 * FH * FW);
                    pf[s][3] = *(const float4*)(src + 3 * FH * FW);
                }
            }
            u_a[s] = act;
        }
    };

    auto WRITE_PATCH = [&]() {
#pragma unroll
        for (int s = 0; s < 2; ++s) {
            if (u_a[s]) {
                float* dl = &patch[u_dl[s]];
                const int q = u_q[s], m = u_m[s];
                *(float4*)(dl + (((0 | q) ^ m) << 2)) =
                    make_float4(pf[s][0].x, pf[s][1].x, pf[s][2].x, pf[s][3].x);
                *(float4*)(dl + (((2 | q) ^ m) << 2)) =
                    make_float4(pf[s][0].y, pf[s][1].y, pf[s][2].y, pf[s][3].y);
                *(float4*)(dl + (((4 | q) ^ m) << 2)) =
                    make_float4(pf[s][0].z, pf[s][1].z, pf[s][2].z, pf[s][3].z);
                *(float4*)(dl + (((6 | q) ^ m) << 2)) =
                    make_float4(pf[s][0].w, pf[s][1].w, pf[s][2].w, pf[s][3].w);
            }
        }
    };

    auto PA = [&]() {
        if (a1) {
            float ax = 0.0f, ay = 0.0f, az = 0.0f, aw = 0.0f;
#pragma unroll
            for (int ii = 0; ii < 6; ++ii) {
                const float w = wxa[ii];
                const int i = bi1 + ii, i4 = i >> 2, il = i & 3;
                const int slot = ((il << 1) | q1) ^ ((j1r + i4) & 7);
                const float4 v = *(const float4*)(&patch[(j1r * NL + i4) * 32 + (slot << 2)]);
                ax += w * v.x; ay += w * v.y; az += w * v.z; aw += w * v.w;
            }
            *(float4*)(&rs[((size_t)pw1 * MAXJ + j1r) * CB + ((q1 ^ (j1r & 1)) << 2)]) =
                make_float4(ax, ay, az, aw);
        }
        if (a2) {
            float ax = 0.0f, ay = 0.0f, az = 0.0f, aw = 0.0f;
#pragma unroll
            for (int ii = 0; ii < 6; ++ii) {
                const float w = wxb[ii];
                const int i = bi2 + ii, i4 = i >> 2, il = i & 3;
                const int slot = ((il << 1) | q2) ^ ((j2r + i4) & 7);
                const float4 v = *(const float4*)(&patch[(j2r * NL + i4) * 32 + (slot << 2)]);
                ax += w * v.x; ay += w * v.y; az += w * v.z; aw += w * v.w;
            }
            *(float4*)(&rs[((size_t)pw2 * MAXJ + j2r) * CB + ((q2 ^ (j2r & 1)) << 2)]) =
                make_float4(ax, ay, az, aw);
        }
    };

    auto PB = [&](int cr, int cc0) {
        const int bin = tid & 63, cp = tid >> 6;
        if (bin < NBINS) {
            const int phv = bin / PW, pwv = bin - phv * PW;
            const int bj = __float_as_int(pbuf[84 + phv]);
            const float inv_area = pbuf[98];
            const int qh = cp >> 1, lo = (cp & 1) * 2;
            float ax = 0.0f, ay = 0.0f;
#pragma unroll
            for (int jj = 0; jj < 6; ++jj) {
                const int j = bj + jj;
                const float w = pbuf[phv * 6 + jj];
                const float2 v = *(const float2*)(
                    &rs[((size_t)pwv * MAXJ + j) * CB + ((qh ^ (j & 1)) << 2) + lo]);
                ax += w * v.x; ay += w * v.y;
            }
            float* o = out + ((size_t)cr * CH + cc0 + 2 * cp) * NBINS + bin;
            o[0]     = ax * inv_area;
            o[NBINS] = ay * inv_area;
        }
    };

    // ---- prologue: item 0 (cold latency exposed once per block) ----
    DECODE(base);
    CALC_WX();
    CALC_WY();
    ISSUE();                    // loads for item 0
    WRITE_PATCH();              // waits vmcnt, stages patch(0)
    int cur_r = rN, cur_c0 = c0N;
    if (n > 1) DECODE(base + 1);

    // ---- steady-state loop: 2 barriers per item ----
    for (int k = 0; k < n; ++k) {
        __syncthreads();                    // bar1: patch(k) ready, rs free
        const bool more = (k + 1 < n);
        if (more) ISSUE();                  // issue loads for item k+1 (regs)
        PA();                               // patch(k) -> rs(k)
        __syncthreads();                    // bar2
        PB(cur_r, cur_c0);                  // rs(k) -> out
        if (more) {
            WRITE_PATCH();                  // pf -> patch(k+1), overlapped loads
            if (rN != cur_r) {              // block-uniform branch
                __syncthreads();            // all PB(k) pbuf readers done
                CALC_WX();
                CALC_WY();
            }
            cur_r = rN; cur_c0 = c0N;
            if (k + 2 < n) DECODE(base + k + 2);
        }
    }
}

extern "C" void kernel_launch(void* const* d_in, const int* in_sizes, int n_in,
                              void* d_out, int out_size, void* d_ws, size_t ws_size,
                              hipStream_t stream) {
    const float* feat = (const float*)d_in[0];
    const float* rois = (const float*)d_in[1];
    float* out = (float*)d_out;
    (void)d_ws; (void)ws_size;

    prroi_pers<<<dim3(NBLK), 256, 0, stream>>>(feat, rois, out);
}

// Round 4
// 86.363 us; speedup vs baseline: 1.1909x; 1.1909x over previous
//
#include <hip/hip_runtime.h>

// PrRoIPool2D forward, MI355X. B=8, C=256, H=W=48, R=300, 7x7 bins, scale=1/16.
// R14: BARRIER-FREE, one item per WAVE (item = r x 2 channels).
//  - R13 counters: all pipes <30% busy, occupancy 22.5% -> latency-bound,
//    block-lockstep stalls. Fix: wave-private LDS slice (6.5 KB: patch+rs),
//    intra-wave s_waitcnt lgkmcnt(0) fences only, NO __syncthreads.
//  - grid dim3(32,300): HW dynamic balance; cblk%8 -> XCD channel partition
//    (2.36 MB/XCD L2 working set).
//  - 6 blocks/CU x 4 independent waves = 24 independent waves/CU latency-hiding.
//  - prep+prm table kept (R10 beat redundant decode); d_ws poison is sunk cost.
//  - patch swizzle off ^ ((j&7)<<1): collision-free (row neighbors sharing a
//    16-float block differ by XOR-1 -> stay in own half); P1 b64 writes 2-way.
// Numerics: identical reduction order/forms as R10-R13 (x taps ii=0..5 then
// y taps jj=0..5, then *inv_area) -> absmax unchanged.

#define PH 7
#define PW 7
#define NBINS 49
#define SCALE 0.0625f
#define CH 256
#define FH 48
#define FW 48
#define RNUM 300
#define MAXJ 23              // max patch rows
#define PRM 112              // param stride per roi (floats)
#define PATCHF (MAXJ * 28 * 2)   // 1288 floats: [j][i(28)][c2]
#define RSF 328                  // 7*23*2 = 322, padded
// prm layout: [0+ph*6]: wy[7][6] | [42+pw*6]: wx[7][6] | [84+ph]: bj (int)
// [91+pw]: bi (int) | [98]: inv_area | [99]: b | [100]: J0 | [101]: I0
// [102]: JROWS | [103]: NI4   (ints stored as float bit patterns)

__device__ __forceinline__ float hat_int(float x, float g) {
    float t = x - (g - 1.0f);
    if (t <= 0.0f) return 0.0f;
    if (t <= 1.0f) return 0.5f * t * t;
    if (t <= 2.0f) { float u = 2.0f - t; return 1.0f - 0.5f * u * u; }
    return 1.0f;
}

// ---- prep: per-roi windows/weights/bounds, once (R10 form) ----
__global__ __launch_bounds__(256)
void prroi_prep(const float* __restrict__ rois, float* __restrict__ prm) {
    const int r = blockIdx.x * 4 + (threadIdx.x >> 6);
    const int t = threadIdx.x & 63;
    if (r >= RNUM || t >= 15) return;

    const float* roi = rois + r * 5;
    const int   b  = (int)roi[0];
    const float x1 = roi[1] * SCALE, y1 = roi[2] * SCALE;
    const float x2 = roi[3] * SCALE, y2 = roi[4] * SCALE;
    const float roi_w = fmaxf(x2 - x1, 0.0f), roi_h = fmaxf(y2 - y1, 0.0f);
    const float bin_w = roi_w / (float)PW, bin_h = roi_h / (float)PH;
    const float area = bin_w * bin_h;
    const float inv_area = (area > 0.0f) ? (1.0f / area) : 0.0f;

    const float ylo = fminf(y1, y2), yhi = fmaxf(y1, y2);
    const float xlo = fminf(x1, x2), xhi = fmaxf(x1, x2);
    const int j1 = min(FH - 1, (int)floorf(yhi) + 1);
    const int i1 = min(FW - 1, (int)floorf(xhi) + 1);
    const int J0 = min(max(0, (int)floorf(ylo) - 1), FH - 6);
    const int I0 = min(max(0, (int)floorf(xlo) - 1) & ~3, FW - 8);
    const int JROWS = min(FH - J0, max(j1 - J0 + 1, 6));        // 6..23
    int NI4 = min(((i1 - I0) >> 2) + 1, (FW - I0) >> 2);
    NI4 = max(NI4, 2);                                           // 2..7

    float* p = prm + (size_t)r * PRM;
    if (t < PH) {
        const int ph = t;
        const float ya = y1 + ph * bin_h, yb = ya + bin_h;
        const int base = min(max((int)floorf(ya) - 1, J0), J0 + JROWS - 6);
        p[84 + ph] = __int_as_float(base - J0);
#pragma unroll
        for (int k = 0; k < 6; ++k) {
            const float g = (float)(base + k);
            p[ph * 6 + k] = hat_int(yb, g) - hat_int(ya, g);
        }
    } else if (t < PH + PW) {
        const int pw = t - PH;
        const float xa = x1 + pw * bin_w, xb = xa + bin_w;
        const int base = min(max((int)floorf(xa) - 1, I0), I0 + 4 * NI4 - 6);
        p[91 + pw] = __int_as_float(base - I0);
#pragma unroll
        for (int k = 0; k < 6; ++k) {
            const float g = (float)(base + k);
            p[42 + pw * 6 + k] = hat_int(xb, g) - hat_int(xa, g);
        }
    } else {                                                     // t == 14
        p[98]  = inv_area;
        p[99]  = __int_as_float(b);
        p[100] = __int_as_float(J0);
        p[101] = __int_as_float(I0);
        p[102] = __int_as_float(JROWS);
        p[103] = __int_as_float(NI4);
    }
}

// ---- main: one item (r, 2 channels) per wave, barrier-free ----
__global__ __launch_bounds__(256, 6)
void prroi_main(const float* __restrict__ feat,
                const float* __restrict__ prm,
                float* __restrict__ out) {
    const int wv   = threadIdx.x >> 6;          // wave 0..3
    const int lane = threadIdx.x & 63;
    const int r    = blockIdx.y;                // 0..299
    const int cblk = blockIdx.x * 4 + wv;       // 0..127
    const int c0   = cblk * 2;

    __shared__ float lds[4][PATCHF + RSF];      // 25856 B -> 6 blocks/CU
    float* patch = lds[wv];
    float* rsw   = lds[wv] + PATCHF;

    const float* p = prm + (size_t)r * PRM;     // uniform -> s_load
    const int b     = __float_as_int(p[99]);
    const int J0    = __float_as_int(p[100]);
    const int I0    = __float_as_int(p[101]);
    const int JROWS = __float_as_int(p[102]);
    const int NI4   = __float_as_int(p[103]);
    const float ia  = p[98];

    // ---- role params (lane-varying, issued early; L1/L2-hot prm) ----
    const int pwA = lane >> 3;                  // 0..7 (valid < 7)
    const int jsl = lane & 7;
    const bool actA = lane < 56;
    float wx[6]; int bi = 0;
    if (actA) {
        bi = __float_as_int(p[91 + pwA]);
#pragma unroll
        for (int k = 0; k < 6; ++k) wx[k] = p[42 + pwA * 6 + k];
    }
    const bool actB = lane < NBINS;
    int bj = 0, pwB = 0;
    float wy[6];
    if (actB) {
        const int ph = lane / 7;                // const-div -> magic mul
        pwB = lane - ph * 7;
        bj = __float_as_int(p[84 + ph]);
#pragma unroll
        for (int k = 0; k < 6; ++k) wy[k] = p[ph * 6 + k];
    }

    // ---- P1: stage patch [j][i][c2], swizzled (off ^ (j&7)<<1) ----
    const float* fb = feat + (size_t)(b * CH + c0) * (FH * FW);
    const int NU = JROWS << 3;                  // (j, i4) units, i4 in 0..7
    for (int u = lane; u < NU; u += 64) {
        const int j = u >> 3, i4 = u & 7;
        if (i4 < NI4) {
            const float* src = fb + (size_t)(J0 + j) * FW + I0 + 4 * i4;
            const float4 a = *(const float4*)src;              // channel c0
            const float4 c = *(const float4*)(src + FH * FW);  // channel c0+1
            const int base = j * 56 + 8 * i4;
            const int sw = (j & 7) << 1;
            *(float2*)&patch[(base + 0) ^ sw] = make_float2(a.x, c.x);
            *(float2*)&patch[(base + 2) ^ sw] = make_float2(a.y, c.y);
            *(float2*)&patch[(base + 4) ^ sw] = make_float2(a.z, c.z);
            *(float2*)&patch[(base + 6) ^ sw] = make_float2(a.w, c.w);
        }
    }
    // intra-wave fence: this wave's ds_writes visible to its ds_reads
    asm volatile("s_waitcnt lgkmcnt(0)" ::: "memory");

    // ---- PA: rs[pw][j][c2] = sum_i wx * patch ----
    if (actA) {
        for (int j = jsl; j < JROWS; j += 8) {
            const int rowb = j * 56 + 2 * bi;
            const int sw = (j & 7) << 1;
            float ax = 0.0f, ay = 0.0f;
#pragma unroll
            for (int ii = 0; ii < 6; ++ii) {
                const float2 v = *(const float2*)&patch[(rowb + 2 * ii) ^ sw];
                ax += wx[ii] * v.x; ay += wx[ii] * v.y;
            }
            *(float2*)&rsw[(pwA * MAXJ + j) * 2] = make_float2(ax, ay);
        }
    }
    asm volatile("s_waitcnt lgkmcnt(0)" ::: "memory");

    // ---- PB: out[bin][c2] = sum_j wy * rs ----
    if (actB) {
        float ax = 0.0f, ay = 0.0f;
#pragma unroll
        for (int jj = 0; jj < 6; ++jj) {
            const float2 v = *(const float2*)&rsw[(pwB * MAXJ + (bj + jj)) * 2];
            ax += wy[jj] * v.x; ay += wy[jj] * v.y;
        }
        float* o = out + ((size_t)r * CH + c0) * NBINS + lane;
        o[0]     = ax * ia;                     // channel c0, contiguous bins
        o[NBINS] = ay * ia;                     // channel c0+1
    }
}

extern "C" void kernel_launch(void* const* d_in, const int* in_sizes, int n_in,
                              void* d_out, int out_size, void* d_ws, size_t ws_size,
                              hipStream_t stream) {
    const float* feat = (const float*)d_in[0];
    const float* rois = (const float*)d_in[1];
    float* out = (float*)d_out;
    float* prm = (float*)d_ws;   // 300 * 112 * 4 = 134.4 KB (poison is sunk cost)

    prroi_prep<<<(RNUM + 3) / 4, 256, 0, stream>>>(rois, prm);
    prroi_main<<<dim3(32, RNUM), 256, 0, stream>>>(feat, prm, out);
}